// Round 10
// baseline (2639.525 us; speedup 1.0000x reference)
//
#include <hip/hip_runtime.h>
#include <hip/hip_bf16.h>
#include <cstdint>
#include <cstddef>

#define N_NODES 32768
#define N_EDGES 131072
#define ET_EDGES (N_EDGES + N_NODES)
#define N_ROOTS 1024
#define EMB_D 256
#define FEAT 128
#define SEQ 16
#define OUT_CH 125

static inline int cdiv(long long a, long long b) { return (int)((a + b - 1) / b); }

typedef short short8 __attribute__((ext_vector_type(8)));
typedef short short4v __attribute__((ext_vector_type(4)));
typedef float f32x4 __attribute__((ext_vector_type(4)));

// ---------- small utils ----------
__device__ __forceinline__ float warpReduceSum(float v) {
#pragma unroll
    for (int m = 32; m; m >>= 1) v += __shfl_xor(v, m, 64);
    return v;
}
__device__ __forceinline__ int encf(float f) {
    int i = __float_as_int(f);
    return i >= 0 ? i : (i ^ 0x7fffffff);
}
__device__ __forceinline__ float decf(int i) {
    return __int_as_float(i >= 0 ? i : (i ^ 0x7fffffff));
}
// fp32 -> bf16 (RNE) scalar
__device__ __forceinline__ short f2bs(float x) {
    unsigned u = __float_as_uint(x);
    u += 0x7fffu + ((u >> 16) & 1u);
    return (short)(u >> 16);
}
// packed pair (v_cvt_pk_bf16_f32)
__device__ __forceinline__ short2 f2bs2(float a, float b) {
    union {
        __hip_bfloat162 h;
        short2 s;
    } u;
    u.h = __float22bfloat162_rn(make_float2(a, b));
    return u.s;
}
__device__ __forceinline__ float bs2f(short s) {
    return __uint_as_float(((unsigned)(unsigned short)s) << 16);
}

__global__ void fill_i32(int* p, int v, int n) {
    int i = blockIdx.x * 256 + threadIdx.x;
    if (i < n) p[i] = v;
}

// cat cols 0..255 pre-initialized with GAT1/GCN1 biases (scatters accumulate on top)
__global__ void init_cat(float* __restrict__ cat, const float* __restrict__ b1, const float* __restrict__ b2) {
    int i = blockIdx.x * 256 + threadIdx.x;  // over N*256
    int n = i >> 8, c = i & 255;
    float b = (c < 128) ? b1[c] : b2[c - 128];
    cat[(size_t)n * 512 + c] = b;
}

// pack all 4 conv kernels into W_all[512][2048] bf16 (row=(Kidx*125+oc), col=k*256+ic)
__global__ void repack_wall(const float* __restrict__ cw0, const float* __restrict__ cw1,
                            const float* __restrict__ cw2, const float* __restrict__ cw3,
                            __hip_bfloat16* __restrict__ wall) {
    int i = blockIdx.x * 256 + threadIdx.x;
    if (i >= 512 * 2048) return;
    int r = i >> 11, c = i & 2047;
    int k = c >> 8, ic = c & 255;
    float v = 0.f;
    if (r < 500) {
        int Kidx = r / 125, oc = r - Kidx * 125;
        int K = 5 + Kidx;
        if (k < K) {
            const float* cw = Kidx == 0 ? cw0 : Kidx == 1 ? cw1 : Kidx == 2 ? cw2 : cw3;
            v = cw[((size_t)oc * 256 + ic) * K + k];
        }
    }
    wall[i] = __float2bfloat16(v);
}

// transformer weights: wqkvT[768][256] bf16, woT[256][256], bqkv[768]
__global__ void repack_xf(const float* __restrict__ Wq, const float* __restrict__ Wk, const float* __restrict__ Wv,
                          const float* __restrict__ Wo, const float* __restrict__ bq, const float* __restrict__ bk,
                          const float* __restrict__ bv, short* __restrict__ wqkvT, short* __restrict__ woT,
                          float* __restrict__ bqkv) {
    int i = blockIdx.x * 256 + threadIdx.x;
    if (i < 768 * 256) {
        int n = i >> 8, k = i & 255;
        const float* W = n < 256 ? Wq : n < 512 ? Wk : Wv;
        wqkvT[i] = f2bs(W[k * 256 + (n & 255)]);
    }
    if (i < 256 * 256) {
        int n = i >> 8, k = i & 255;
        woT[i] = f2bs(Wo[k * 256 + n]);
    }
    if (i < 768) bqkv[i] = i < 256 ? bq[i] : i < 512 ? bk[i - 256] : bv[i - 512];
}

// generic W[K][N] fp32 -> Wt[N][K] bf16
__global__ void repack_wT(const float* __restrict__ W, short* __restrict__ out, int K, int N) {
    int i = blockIdx.x * 256 + threadIdx.x;
    if (i >= K * N) return;
    int n = i / K, k = i - n * K;
    out[i] = f2bs(W[(size_t)k * N + n]);
}

// ---------- MFMA GEMM: C[M,128] = A[M,K]fp32 @ Wt[128,K]bf16^T ; M mult of 128, K mult of 32 ----------
__global__ __launch_bounds__(256) void mfma_gemm_n128(const float* __restrict__ A, const short* __restrict__ Wt,
                                                      float* __restrict__ C, int K) {
    __shared__ short As[128 * 40];
    __shared__ short Bs[128 * 40];
    const int m0 = blockIdx.x * 128;
    const int tid = threadIdx.x;
    const int lane = tid & 63;
    const int wave = tid >> 6;
    const int wm = (wave >> 1) * 64, wn = (wave & 1) * 64;
    const int quad = lane >> 4, l16 = lane & 15;

    const int r0 = tid >> 2, kc = (tid & 3) * 8;
    const int r1 = r0 + 64;

    f32x4 acc[4][4];
#pragma unroll
    for (int i = 0; i < 4; i++)
#pragma unroll
        for (int j = 0; j < 4; j++) acc[i][j] = (f32x4){0.f, 0.f, 0.f, 0.f};

    for (int k0 = 0; k0 < K; k0 += 32) {
#pragma unroll
        for (int rr = 0; rr < 2; rr++) {
            const int r = rr ? r1 : r0;
            const float* pa = A + (size_t)(m0 + r) * K + k0 + kc;
            float4 a0 = ((const float4*)pa)[0], a1 = ((const float4*)pa)[1];
            short2 c0 = f2bs2(a0.x, a0.y), c1 = f2bs2(a0.z, a0.w), c2 = f2bs2(a1.x, a1.y), c3 = f2bs2(a1.z, a1.w);
            *(short8*)(As + r * 40 + kc) = (short8){c0.x, c0.y, c1.x, c1.y, c2.x, c2.y, c3.x, c3.y};
        }
        *(short8*)(Bs + r0 * 40 + kc) = *(const short8*)(Wt + (size_t)r0 * K + k0 + kc);
        *(short8*)(Bs + r1 * 40 + kc) = *(const short8*)(Wt + (size_t)r1 * K + k0 + kc);
        __syncthreads();
        short8 af[4], bfr[4];
#pragma unroll
        for (int i = 0; i < 4; i++) af[i] = *(const short8*)(As + (wm + i * 16 + l16) * 40 + quad * 8);
#pragma unroll
        for (int j = 0; j < 4; j++) bfr[j] = *(const short8*)(Bs + (wn + j * 16 + l16) * 40 + quad * 8);
#pragma unroll
        for (int i = 0; i < 4; i++)
#pragma unroll
            for (int j = 0; j < 4; j++)
                acc[i][j] = __builtin_amdgcn_mfma_f32_16x16x32_bf16(af[i], bfr[j], acc[i][j], 0, 0, 0);
        __syncthreads();
    }
#pragma unroll
    for (int i = 0; i < 4; i++) {
#pragma unroll
        for (int j = 0; j < 4; j++) {
            const int col = wn + j * 16 + l16;
            const size_t base = (size_t)(m0 + wm + i * 16 + quad * 4) * 128 + col;
#pragma unroll
            for (int r = 0; r < 4; r++) C[base + (size_t)r * 128] = acc[i][j][r];
        }
    }
}

// ---------- generic fp32 GEMM (head fc1 only) ----------
__global__ __launch_bounds__(256) void gemm64(const float* __restrict__ A, const float* __restrict__ B,
                                              const float* __restrict__ bias, float* __restrict__ C,
                                              int M, int N, int K, int lda, int ldc, int doRelu) {
    __shared__ float As[16][65];
    __shared__ float Bs[16][65];
    const int bm = blockIdx.y * 64, bn = blockIdx.x * 64;
    const int tid = threadIdx.x;
    const int tx = tid & 15, ty = tid >> 4;
    float acc[4][4] = {};
    for (int k0 = 0; k0 < K; k0 += 16) {
#pragma unroll
        for (int j = 0; j < 4; j++) {
            int i = tid + j * 256;
            int kk = i & 15, m = i >> 4;
            int gr = bm + m, gc = k0 + kk;
            As[kk][m] = (gr < M && gc < K) ? A[(size_t)gr * lda + gc] : 0.f;
        }
#pragma unroll
        for (int j = 0; j < 4; j++) {
            int i = tid + j * 256;
            int n = i & 63, kk = i >> 6;
            int gr = k0 + kk, gc = bn + n;
            Bs[kk][n] = (gr < K && gc < N) ? B[(size_t)gr * N + gc] : 0.f;
        }
        __syncthreads();
#pragma unroll
        for (int kk = 0; kk < 16; kk++) {
            float a[4], b[4];
#pragma unroll
            for (int i2 = 0; i2 < 4; i2++) a[i2] = As[kk][ty * 4 + i2];
#pragma unroll
            for (int j2 = 0; j2 < 4; j2++) b[j2] = Bs[kk][tx * 4 + j2];
#pragma unroll
            for (int i2 = 0; i2 < 4; i2++)
#pragma unroll
                for (int j2 = 0; j2 < 4; j2++) acc[i2][j2] = fmaf(a[i2], b[j2], acc[i2][j2]);
        }
        __syncthreads();
    }
#pragma unroll
    for (int i2 = 0; i2 < 4; i2++) {
        int r = bm + ty * 4 + i2;
        if (r >= M) continue;
#pragma unroll
        for (int j2 = 0; j2 < 4; j2++) {
            int c = bn + tx * 4 + j2;
            if (c >= N) continue;
            float v = acc[i2][j2];
            if (bias) v += bias[c];
            if (doRelu) v = fmaxf(v, 0.f);
            C[(size_t)r * ldc + c] = v;
        }
    }
}

// ---------- GAT alphas ----------
__global__ __launch_bounds__(256) void alpha_kernel(const float* __restrict__ h, const float* __restrict__ asrc,
                                                    const float* __restrict__ adst, float* __restrict__ als,
                                                    float* __restrict__ ald) {
    int gw = (blockIdx.x * 256 + threadIdx.x) >> 6;
    int lane = threadIdx.x & 63;
    if (gw >= N_NODES) return;
    const float* row = h + (size_t)gw * FEAT;
    float v0 = row[lane], v1 = row[lane + 64];
    float ps = v0 * asrc[lane] + v1 * asrc[lane + 64];
    float pd = v0 * adst[lane] + v1 * adst[lane + 64];
    ps = warpReduceSum(ps);
    pd = warpReduceSum(pd);
    if (lane == 0) {
        als[gw] = ps;
        ald[gw] = pd;
    }
}

// ---------- edge passes ----------
__device__ __forceinline__ void edge_decode(int i, const int* __restrict__ ei, int& s, int& d) {
    if (i < N_EDGES) {
        s = ei[i];
        d = ei[N_EDGES + i];
    } else {
        s = d = i - N_EDGES;
    }
}

__global__ void edge_p1(const int* __restrict__ ei, const float* __restrict__ als, const float* __restrict__ ald,
                        float* __restrict__ elog, int* __restrict__ menc, float* dega) {
    int i = blockIdx.x * 256 + threadIdx.x;
    if (i >= ET_EDGES) return;
    int s, d;
    edge_decode(i, ei, s, d);
    float e = als[s] + ald[d];
    e = (e >= 0.f) ? e : 0.2f * e;
    elog[i] = e;
    atomicMax(&menc[d], encf(e));
    if (dega) unsafeAtomicAdd(&dega[d], 1.f);
}

__global__ void edge_p2(const int* __restrict__ ei, float* __restrict__ elog, const int* __restrict__ menc,
                        float* __restrict__ den) {
    int i = blockIdx.x * 256 + threadIdx.x;
    if (i >= ET_EDGES) return;
    int s, d;
    edge_decode(i, ei, s, d);
    float ex = __expf(elog[i] - decf(menc[d]));
    elog[i] = ex;
    unsafeAtomicAdd(&den[d], ex);
}

__global__ void dinv_kernel(float* deg) {
    int i = blockIdx.x * 256 + threadIdx.x;
    if (i < N_NODES) deg[i] = rsqrtf(fmaxf(deg[i], 1.f));
}

// Fused GAT1+GCN1 scatter, float4 per thread: 4x fewer edge decodes / coef loads than per-element.
__global__ void scatter_fused1(const int* __restrict__ ei, const float* __restrict__ elog,
                               const float* __restrict__ den, const float* __restrict__ dinv,
                               const float* __restrict__ h1, const float* __restrict__ h2,
                               float* __restrict__ cat) {
    int i = blockIdx.x * 256 + threadIdx.x;  // over ET_EDGES * 32
    if (i >= ET_EDGES * 32) return;
    int e = i >> 5, f4 = (i & 31) * 4;
    int s, d;
    edge_decode(e, ei, s, d);
    float cA = elog[e] / den[d];
    float cG = dinv[s] * dinv[d];
    float4 a = *(const float4*)(h1 + (size_t)s * FEAT + f4);
    float4 g = *(const float4*)(h2 + (size_t)s * FEAT + f4);
    float* oA = cat + (size_t)d * 512 + f4;
    float* oG = cat + (size_t)d * 512 + 128 + f4;
    unsafeAtomicAdd(oA + 0, cA * a.x);
    unsafeAtomicAdd(oA + 1, cA * a.y);
    unsafeAtomicAdd(oA + 2, cA * a.z);
    unsafeAtomicAdd(oA + 3, cA * a.w);
    unsafeAtomicAdd(oG + 0, cG * g.x);
    unsafeAtomicAdd(oG + 1, cG * g.y);
    unsafeAtomicAdd(oG + 2, cG * g.z);
    unsafeAtomicAdd(oG + 3, cG * g.w);
}

// GAT2 scatter with inline den division, float4 per thread
__global__ void edge_scatter_div(const int* __restrict__ ei, const float* __restrict__ elog,
                                 const float* __restrict__ den, const float* __restrict__ h,
                                 float* __restrict__ out) {
    int i = blockIdx.x * 256 + threadIdx.x;  // over ET_EDGES * 32
    if (i >= ET_EDGES * 32) return;
    int e = i >> 5, f4 = (i & 31) * 4;
    int s, d;
    edge_decode(e, ei, s, d);
    float coef = elog[e] / den[d];
    float4 a = *(const float4*)(h + (size_t)s * FEAT + f4);
    float* o = out + (size_t)d * FEAT + f4;
    unsafeAtomicAdd(o + 0, coef * a.x);
    unsafeAtomicAdd(o + 1, coef * a.y);
    unsafeAtomicAdd(o + 2, coef * a.z);
    unsafeAtomicAdd(o + 3, coef * a.w);
}

__global__ void root_gather(const float* __restrict__ g2, const int* __restrict__ rooti, const float* __restrict__ gb,
                            float* __restrict__ fin) {
    int i = blockIdx.x * 256 + threadIdx.x;
    if (i >= N_ROOTS * FEAT) return;
    int r = i >> 7, c = i & 127;
    fin[(size_t)r * 1128 + c] = g2[(size_t)rooti[r] * FEAT + c] + gb[c];
}

__global__ void fc2_kernel(const float* __restrict__ fch, const float* __restrict__ W, const float* __restrict__ b,
                           float* __restrict__ out) {
    int i = blockIdx.x * 256 + threadIdx.x;
    if (i >= N_ROOTS * 3) return;
    int r = i / 3, c = i - r * 3;
    float acc = b[c];
    for (int k = 0; k < 300; k++) acc = fmaf(fch[(size_t)r * 300 + k], W[k * 3 + c], acc);
    out[i] = acc;
}

// ================= MFMA transformer v9 (PROVEN BEST: 1166-1180us, 84 VGPR, 35% occ) =================
// Occupancy law established over 9 rounds: waves/SIMD = floor(256 / VGPR) (unified-file scheduling
// budget ~256/SIMD), then LDS caps blocks. v9: 84 regs -> 3 waves/SIMD; 48KB LDS -> 3 blocks; both
// bind at 12 waves/CU (35%). All escapes measured closed: cap<live spills (R0/1/6/7), more ILP
// spills (R5), 512-thr quantizes worse (R8), async B-ring / big-GEMM restructure EV-neutral on paper.
// LDS layout: addr(shorts) = row*256 + (col ^ ((row&7)<<3)). XOR hits byte-bits 4-6 (16-B granule).
__device__ __forceinline__ int lsw(int row, int col) {
    return row * 256 + (col ^ ((row & 7) << 3));
}

// vT layout (wave-private): addr(shorts) = d*32 + swizzled key
__device__ __forceinline__ int vt_addr(int d, int key) {
    return d * 32 + (((key & 24) ^ (((d ^ (d >> 2)) & 3) << 3)) | (key & 7));
}

template <int MODE>
__global__ __launch_bounds__(256, 3) void xformer_kernel(
    const float* __restrict__ emb, const int* __restrict__ text2, const short* __restrict__ wqkvT,
    const float* __restrict__ bqkv, const short* __restrict__ woT, const float* __restrict__ bo,
    const float* __restrict__ lng, const float* __restrict__ lnb, const int* __restrict__ rooti,
    const int* __restrict__ rpi, float* __restrict__ cat, unsigned short* __restrict__ tbuf) {
    __shared__ short qa[32 * 256];    // Q -> P-scratch -> attn-out -> fp32 LN scratch
    __shared__ short kreg[32 * 256];  // A-tile -> y
    __shared__ short vbuf[32 * 256];  // per-wave 2048-short regions: K -> vT
    // total LDS 49152 B -> 3 blocks/CU

    const int tid = threadIdx.x;
    const int wave = tid >> 6, lane = tid & 63;
    const int quad = lane >> 4, l16 = lane & 15;

    int gnode[2];
#pragma unroll
    for (int m = 0; m < 2; m++) {
        int slot = blockIdx.x * 2 + m;
        gnode[m] = (MODE == 0) ? slot : ((slot < N_ROOTS) ? rooti[slot] : rpi[slot - N_ROOTS]);
    }

    // ---- Stage A-tile (2 nodes x 16 rows x 256 cols, bf16) into kreg; one gather pass ----
    {
        const int row = tid >> 3, seg = tid & 7;  // row 0..31, seg 0..7 (32 cols each)
        const int m = row >> 4, r = row & 15;
        const int tok = text2[gnode[m] * SEQ + r];
        const float* ep = emb + (size_t)tok * 256 + seg * 32;
#pragma unroll
        for (int j = 0; j < 4; j++) {
            float4 ea = ((const float4*)(ep + j * 8))[0];
            float4 eb = ((const float4*)(ep + j * 8))[1];
            short2 w0 = f2bs2(ea.x, ea.y), w1 = f2bs2(ea.z, ea.w);
            short2 w2 = f2bs2(eb.x, eb.y), w3 = f2bs2(eb.z, eb.w);
            *(short8*)(kreg + lsw(row, seg * 32 + j * 8)) =
                (short8){w0.x, w0.y, w1.x, w1.y, w2.x, w2.y, w3.x, w3.y};
        }
    }
    __syncthreads();

    // Half-GEMM: 2 output col-tiles (32 cols), acc[2][2], 1-deep B prefetch.
    auto run_gemm_h = [&](const short* __restrict__ W, int wrow0, const short* __restrict__ Albase,
                          f32x4(&acc)[2][2]) {
#pragma unroll
        for (int i = 0; i < 2; i++) {
            acc[i][0] = (f32x4){0.f, 0.f, 0.f, 0.f};
            acc[i][1] = (f32x4){0.f, 0.f, 0.f, 0.f};
        }
        const short* wb = W + (size_t)(wrow0 + l16) * 256 + quad * 8;
        short8 B0 = *(const short8*)(wb);
        short8 B1 = *(const short8*)(wb + 16 * 256);
#pragma unroll
        for (int k0 = 0; k0 < 8; k0++) {
            short8 B0n, B1n;
            if (k0 < 7) {
                B0n = *(const short8*)(wb + (k0 + 1) * 32);
                B1n = *(const short8*)(wb + 16 * 256 + (k0 + 1) * 32);
            }
            short8 A0 = *(const short8*)(Albase + lsw(l16, k0 * 32 + quad * 8));
            short8 A1 = *(const short8*)(Albase + lsw(16 + l16, k0 * 32 + quad * 8));
            acc[0][0] = __builtin_amdgcn_mfma_f32_16x16x32_bf16(A0, B0, acc[0][0], 0, 0, 0);
            acc[0][1] = __builtin_amdgcn_mfma_f32_16x16x32_bf16(A1, B0, acc[0][1], 0, 0, 0);
            acc[1][0] = __builtin_amdgcn_mfma_f32_16x16x32_bf16(A0, B1, acc[1][0], 0, 0, 0);
            acc[1][1] = __builtin_amdgcn_mfma_f32_16x16x32_bf16(A1, B1, acc[1][1], 0, 0, 0);
            B0 = B0n;
            B1 = B1n;
        }
    };

    // K private-layout address inside this wave's vbuf region (row 0..31, c 0..63)
    auto kpriv = [&](int row, int c) { return wave * 2048 + row * 64 + (c ^ ((row & 7) << 3)); };

    f32x4 acc[2][2];

    // ---- Phase 1a: Q halves -> qa (wave-local cols) ----
#pragma unroll 1
    for (int hh = 0; hh < 2; hh++) {
        run_gemm_h(wqkvT, (wave * 4 + hh * 2) * 16, kreg, acc);
#pragma unroll
        for (int ii = 0; ii < 2; ii++) {
            const int col = (wave * 4 + hh * 2 + ii) * 16 + l16;
            const float b = bqkv[col];
#pragma unroll
            for (int m = 0; m < 2; m++) {
                const int rbase = m * 16 + quad * 4;
                short2 p01 = f2bs2((acc[ii][m][0] + b) * 0.25f, (acc[ii][m][1] + b) * 0.25f);
                short2 p23 = f2bs2((acc[ii][m][2] + b) * 0.25f, (acc[ii][m][3] + b) * 0.25f);
                qa[lsw(rbase + 0, col)] = p01.x;
                qa[lsw(rbase + 1, col)] = p01.y;
                qa[lsw(rbase + 2, col)] = p23.x;
                qa[lsw(rbase + 3, col)] = p23.y;
            }
        }
    }
    // ---- Phase 1b: K halves -> vbuf private region (only this wave reads its K cols) ----
#pragma unroll 1
    for (int hh = 0; hh < 2; hh++) {
        run_gemm_h(wqkvT, (16 + wave * 4 + hh * 2) * 16, kreg, acc);
#pragma unroll
        for (int ii = 0; ii < 2; ii++) {
            const int i = hh * 2 + ii;
            const int c = i * 16 + l16;
            const float b = bqkv[(16 + wave * 4 + i) * 16 + l16];
#pragma unroll
            for (int m = 0; m < 2; m++) {
                const int rbase = m * 16 + quad * 4;
                short2 p01 = f2bs2(acc[ii][m][0] + b, acc[ii][m][1] + b);
                short2 p23 = f2bs2(acc[ii][m][2] + b, acc[ii][m][3] + b);
                vbuf[kpriv(rbase + 0, c)] = p01.x;
                vbuf[kpriv(rbase + 1, c)] = p01.y;
                vbuf[kpriv(rbase + 2, c)] = p23.x;
                vbuf[kpriv(rbase + 3, c)] = p23.y;
            }
        }
    }
    // Q/K for heads wave*4..+3 are wave-local: no barrier.

    // ---- Phase 2a: S = K·Q^T per (node, head); softmax per column; P -> qa scratch ----
#pragma unroll
    for (int p = 0; p < 2; p++) {
#pragma unroll
        for (int i = 0; i < 4; i++) {
            const int h = wave * 4 + i;
            const int arow = p * 16 + l16;
            const int q8 = (quad & 1) * 8;
            short8 Af = *(const short8*)(vbuf + kpriv(arow, i * 16 + q8));
            short8 Bf = *(const short8*)(qa + lsw(arow, h * 16 + q8));
            if (quad >= 2) {
                Af = (short8){0, 0, 0, 0, 0, 0, 0, 0};
                Bf = (short8){0, 0, 0, 0, 0, 0, 0, 0};
            }
            f32x4 S = __builtin_amdgcn_mfma_f32_16x16x32_bf16(Af, Bf, (f32x4){0.f, 0.f, 0.f, 0.f}, 0, 0, 0);
            float mx = fmaxf(fmaxf(S[0], S[1]), fmaxf(S[2], S[3]));
            mx = fmaxf(mx, __shfl_xor(mx, 16));
            mx = fmaxf(mx, __shfl_xor(mx, 32));
            float e0 = __expf(S[0] - mx), e1 = __expf(S[1] - mx);
            float e2 = __expf(S[2] - mx), e3 = __expf(S[3] - mx);
            float sm = (e0 + e1) + (e2 + e3);
            sm += __shfl_xor(sm, 16);
            sm += __shfl_xor(sm, 32);
            const float inv = 1.f / sm;
            short2 p01 = f2bs2(e0 * inv, e1 * inv), p23 = f2bs2(e2 * inv, e3 * inv);
            *(short4v*)(qa + lsw(arow, h * 16 + quad * 4)) = (short4v){p01.x, p01.y, p23.x, p23.y};
        }
    }

    // ---- Phase 1c: V halves -> vT straight into vbuf private region (this wave's K is dead) ----
#pragma unroll 1
    for (int hh = 0; hh < 2; hh++) {
        run_gemm_h(wqkvT, (32 + wave * 4 + hh * 2) * 16, kreg, acc);
#pragma unroll
        for (int ii = 0; ii < 2; ii++) {
            const int i = hh * 2 + ii;
            const int d = (wave * 4 + i) * 16 + l16;
            const float b = bqkv[(32 + wave * 4 + i) * 16 + l16];
#pragma unroll
            for (int m = 0; m < 2; m++) {
                const int rbase = m * 16 + quad * 4;
                short2 p01 = f2bs2(acc[ii][m][0] + b, acc[ii][m][1] + b);
                short2 p23 = f2bs2(acc[ii][m][2] + b, acc[ii][m][3] + b);
                *(short4v*)(vbuf + vt_addr(d, rbase)) = (short4v){p01.x, p01.y, p23.x, p23.y};
            }
        }
    }

    // ---- Phase 2c: O^T = V^T · P ; O overwrites P-scratch (all wave-local) ----
#pragma unroll
    for (int p = 0; p < 2; p++) {
#pragma unroll
        for (int i = 0; i < 4; i++) {
            const int h = wave * 4 + i;
            const int arow = p * 16 + l16;
            const int q8 = (quad & 1) * 8;
            short8 BP = *(const short8*)(qa + lsw(arow, h * 16 + q8));
            short8 Av = *(const short8*)(vbuf + vt_addr(h * 16 + l16, p * 16 + q8));
            if (quad >= 2) {
                BP = (short8){0, 0, 0, 0, 0, 0, 0, 0};
                Av = (short8){0, 0, 0, 0, 0, 0, 0, 0};
            }
            f32x4 O = __builtin_amdgcn_mfma_f32_16x16x32_bf16(Av, BP, (f32x4){0.f, 0.f, 0.f, 0.f}, 0, 0, 0);
            short2 o01 = f2bs2(O[0], O[1]), o23 = f2bs2(O[2], O[3]);
            *(short4v*)(qa + lsw(arow, h * 16 + quad * 4)) = (short4v){o01.x, o01.y, o23.x, o23.y};
        }
    }
    __syncthreads();  // attn-out crosses waves for O-proj; all A-tile (kreg) reads done

    // ---- Phase 3: O-proj halves (+bo) -> y into kreg (A-tile dead) ----
#pragma unroll 1
    for (int hh = 0; hh < 2; hh++) {
        run_gemm_h(woT, (wave * 4 + hh * 2) * 16, qa, acc);
#pragma unroll
        for (int ii = 0; ii < 2; ii++) {
            const int col = (wave * 4 + hh * 2 + ii) * 16 + l16;
            const float bocol = bo[col];
#pragma unroll
            for (int m = 0; m < 2; m++) {
                const int rbase = m * 16 + quad * 4;
                short2 a01 = f2bs2(acc[ii][m][0] + bocol, acc[ii][m][1] + bocol);
                short2 a23 = f2bs2(acc[ii][m][2] + bocol, acc[ii][m][3] + bocol);
                kreg[lsw(rbase + 0, col)] = a01.x;
                kreg[lsw(rbase + 1, col)] = a01.y;
                kreg[lsw(rbase + 2, col)] = a23.x;
                kreg[lsw(rbase + 3, col)] = a23.y;
            }
        }
    }
    __syncthreads();

    // ---- Phase 4: residual (emb re-read, L2-hot) + LayerNorm ----
    float* qs = (float*)qa;  // qa dead
    {
        const int row = tid >> 3, seg = tid & 7;
        const int m = row >> 4, r = row & 15;
        const int tokr = text2[gnode[m] * SEQ + r];
        const float* ep = emb + (size_t)tokr * 256 + seg * 32;
        float sum = 0.f, sq = 0.f;
#pragma unroll
        for (int j = 0; j < 4; j++) {
            const int base = lsw(row, seg * 32 + j * 8);
            short8 y8 = *(const short8*)(kreg + base);
            float4 ea = ((const float4*)(ep + j * 8))[0];
            float4 eb = ((const float4*)(ep + j * 8))[1];
            float evv[8] = {ea.x, ea.y, ea.z, ea.w, eb.x, eb.y, eb.z, eb.w};
            float yv[8];
#pragma unroll
            for (int e = 0; e < 8; e++) {
                yv[e] = bs2f(y8[e]) + evv[e];
                sum += yv[e];
                sq = fmaf(yv[e], yv[e], sq);
            }
            short2 w0 = f2bs2(yv[0], yv[1]), w1 = f2bs2(yv[2], yv[3]);
            short2 w2 = f2bs2(yv[4], yv[5]), w3 = f2bs2(yv[6], yv[7]);
            *(short4v*)(kreg + base) = (short4v){w0.x, w0.y, w1.x, w1.y};
            *(short4v*)(kreg + base + 4) = (short4v){w2.x, w2.y, w3.x, w3.y};
        }
        qs[tid] = sum;
        qs[256 + tid] = sq;
    }
    __syncthreads();
    if (tid < 32) {
        float s = 0.f, q2 = 0.f;
#pragma unroll
        for (int j = 0; j < 8; j++) {
            s += qs[tid * 8 + j];
            q2 += qs[256 + tid * 8 + j];
        }
        float mu = s * (1.f / 256.f);
        float var = q2 * (1.f / 256.f) - mu * mu;
        qs[512 + tid * 2] = mu;
        qs[512 + tid * 2 + 1] = rsqrtf(var + 1e-5f);
    }
    __syncthreads();
    {
        const int c = tid;
        const float g = lng[c], bb = lnb[c];
        float csum[2] = {0.f, 0.f};
#pragma unroll
        for (int m = 0; m < 2; m++) {
#pragma unroll
            for (int r = 0; r < 16; r++) {
                const int row = m * 16 + r;
                const float yv = bs2f(kreg[lsw(row, c)]);
                const float mu = qs[512 + row * 2], rstd = qs[512 + row * 2 + 1];
                const float o = (yv - mu) * rstd * g + bb;
                if (MODE == 0) {
                    csum[m] += o;
                } else {
                    tbuf[((size_t)(blockIdx.x * 2 + m) * 24 + r) * 256 + c] = (unsigned short)f2bs(o);
                }
            }
        }
        if (MODE == 0) {
            cat[(size_t)gnode[0] * 512 + 256 + c] = csum[0] * (1.f / 16.f);
            cat[(size_t)gnode[1] * 512 + 256 + c] = csum[1] * (1.f / 16.f);
        } else {
            for (int z = tid; z < 2 * 8 * 256; z += 256) {
                const int m = z >> 11, rem = z & 2047;
                tbuf[((size_t)(blockIdx.x * 2 + m) * 24 + 16 + (rem >> 8)) * 256 + (rem & 255)] = 0;
            }
        }
    }
}

// conv GEMM: C[24576,512] = im2col(tbuf) @ W_all^T. Per-n-tile K cap: tiles 0/1 hold kernel sizes
// 5-6/6-7 only, so wall rows are zero beyond K=1536/1792 -> skip guaranteed-zero MFMA (exact).
__global__ __launch_bounds__(256) void conv_gemm(const short* __restrict__ tb, const short* __restrict__ wall,
                                                 float* __restrict__ C) {
    __shared__ short As[128 * 40];
    __shared__ short Bs[128 * 40];
    const int bid = blockIdx.x;
    const int m0 = (bid >> 2) * 128;
    const int n0 = (bid & 3) * 128;
    const int tid = threadIdx.x;
    const int lane = tid & 63;
    const int wave = tid >> 6;
    const int wm = (wave >> 1) * 64, wn = (wave & 1) * 64;
    const int quad = lane >> 4, l16 = lane & 15;

    const int r0 = tid >> 2, kc = (tid & 3) * 8;
    const int r1 = r0 + 64;
    const int am0 = m0 + r0, am1 = m0 + r1;
    const int s0 = am0 / 12, p0_ = am0 - s0 * 12;
    const int s1 = am1 / 12, p1_ = am1 - s1 * 12;
    const size_t ga0 = (size_t)(s0 * 24 + p0_) * 256 + kc;
    const size_t ga1 = (size_t)(s1 * 24 + p1_) * 256 + kc;
    const size_t gb0 = (size_t)(n0 + r0) * 2048 + kc;
    const size_t gb1 = (size_t)(n0 + r1) * 2048 + kc;
    short* sa0 = As + r0 * 40 + kc;
    short* sa1 = As + r1 * 40 + kc;
    short* sb0 = Bs + r0 * 40 + kc;
    short* sb1 = Bs + r1 * 40 + kc;

    const int kmax = (n0 == 0) ? 1536 : (n0 == 128) ? 1792 : 2048;

    f32x4 acc[4][4];
#pragma unroll
    for (int i = 0; i < 4; i++)
#pragma unroll
        for (int j = 0; j < 4; j++) acc[i][j] = (f32x4){0.f, 0.f, 0.f, 0.f};

    for (int k0 = 0; k0 < kmax; k0 += 32) {
        short8 a0 = *(const short8*)(tb + ga0 + k0);
        short8 a1 = *(const short8*)(tb + ga1 + k0);
        short8 b0 = *(const short8*)(wall + gb0 + k0);
        short8 b1 = *(const short8*)(wall + gb1 + k0);
        *(short8*)sa0 = a0;
        *(short8*)sa1 = a1;
        *(short8*)sb0 = b0;
        *(short8*)sb1 = b1;
        __syncthreads();
        short8 af[4], bfr[4];
#pragma unroll
        for (int i = 0; i < 4; i++) af[i] = *(const short8*)(As + (wm + i * 16 + l16) * 40 + quad * 8);
#pragma unroll
        for (int j = 0; j < 4; j++) bfr[j] = *(const short8*)(Bs + (wn + j * 16 + l16) * 40 + quad * 8);
#pragma unroll
        for (int i = 0; i < 4; i++)
#pragma unroll
            for (int j = 0; j < 4; j++)
                acc[i][j] = __builtin_amdgcn_mfma_f32_16x16x32_bf16(af[i], bfr[j], acc[i][j], 0, 0, 0);
        __syncthreads();
    }
#pragma unroll
    for (int i = 0; i < 4; i++) {
#pragma unroll
        for (int j = 0; j < 4; j++) {
            const int col = n0 + wn + j * 16 + l16;
            const size_t base = (size_t)(m0 + wm + i * 16 + quad * 4) * 512 + col;
#pragma unroll
            for (int r = 0; r < 4; r++) C[base + (size_t)r * 512] = acc[i][j][r];
        }
    }
}

__global__ void conv_maxpool(const float* __restrict__ C, const float* __restrict__ cb0, const float* __restrict__ cb1,
                             const float* __restrict__ cb2, const float* __restrict__ cb3, float* __restrict__ fin) {
    int i = blockIdx.x * 256 + threadIdx.x;
    if (i >= 2048 * 500) return;
    int slot = i / 500, q = i - slot * 500;
    int Kidx = q / 125, oc = q - Kidx * 125;
    int L = 12 - Kidx;
    const float* base = C + (size_t)(slot * 12) * 512 + q;
    float m = base[0];
    for (int p = 1; p < L; p++) m = fmaxf(m, base[(size_t)p * 512]);
    float b = (Kidx == 0 ? cb0 : Kidx == 1 ? cb1 : Kidx == 2 ? cb2 : cb3)[oc];
    float v = fmaxf(m + b, 0.f);
    int idx = slot < N_ROOTS ? slot : slot - N_ROOTS;
    int colbase = slot < N_ROOTS ? 128 : 628;
    fin[(size_t)idx * 1128 + colbase + q] = v;
}

// ---------- host launch ----------
extern "C" void kernel_launch(void* const* d_in, const int* in_sizes, int n_in, void* d_out, int out_size, void* d_ws,
                              size_t ws_size, hipStream_t stream) {
    const float* x2 = (const float*)d_in[0];
    const float* emb = (const float*)d_in[1];
    const float* Wq = (const float*)d_in[2];
    const float* Wk = (const float*)d_in[3];
    const float* Wv = (const float*)d_in[4];
    const float* Wo = (const float*)d_in[5];
    const float* bq = (const float*)d_in[6];
    const float* bk = (const float*)d_in[7];
    const float* bv = (const float*)d_in[8];
    const float* bo = (const float*)d_in[9];
    const float* lng = (const float*)d_in[10];
    const float* lnb = (const float*)d_in[11];
    const float* gat1_W = (const float*)d_in[12];
    const float* gat1_as = (const float*)d_in[13];
    const float* gat1_ad = (const float*)d_in[14];
    const float* gat1_b = (const float*)d_in[15];
    const float* gcn1_W = (const float*)d_in[16];
    const float* gcn1_b = (const float*)d_in[17];
    const float* gat2_W = (const float*)d_in[18];
    const float* gat2_as = (const float*)d_in[19];
    const float* gat2_ad = (const float*)d_in[20];
    const float* gat2_b = (const float*)d_in[21];
    // d_in[22]/[23] gcn2: dead code in reference forward
    const float* cw0 = (const float*)d_in[24];
    const float* cb0 = (const float*)d_in[25];
    const float* cw1 = (const float*)d_in[26];
    const float* cb1 = (const float*)d_in[27];
    const float* cw2 = (const float*)d_in[28];
    const float* cb2 = (const float*)d_in[29];
    const float* cw3 = (const float*)d_in[30];
    const float* cb3 = (const float*)d_in[31];
    const float* fc1_W = (const float*)d_in[32];
    const float* fc1_b = (const float*)d_in[33];
    const float* fc2_W = (const float*)d_in[34];
    const float* fc2_b = (const float*)d_in[35];
    const int* text2 = (const int*)d_in[36];
    const int* ei = (const int*)d_in[37];
    const int* rooti = (const int*)d_in[38];
    const int* rpi = (const int*)d_in[39];

    float* ws = (float*)d_ws;
    size_t off = 0;
    auto alloc = [&](size_t n) {
        float* p = ws + off;
        off += n;
        return p;
    };
    // zero block first (one small memset): g2o | den1 | den2 | deg
    float* g2o = alloc((size_t)N_NODES * FEAT);
    float* den1 = alloc(N_NODES);
    float* den2 = alloc(N_NODES);
    float* deg = alloc(N_NODES);
    size_t zero_floats = off;
    float* cat = alloc((size_t)N_NODES * 512);  // init_cat covers cols 0..255; xformer fills 256..511
    float* h1 = alloc((size_t)N_NODES * FEAT);  // h1+h2 reused as tbuf after scatters
    float* h2 = alloc((size_t)N_NODES * FEAT);
    float* hg2 = alloc((size_t)N_NODES * FEAT);
    float* als1 = alloc(N_NODES);
    float* ald1 = alloc(N_NODES);
    float* als2 = alloc(N_NODES);
    float* ald2 = alloc(N_NODES);
    int* m1 = (int*)alloc(N_NODES);
    int* m2 = (int*)alloc(N_NODES);
    float* el1 = alloc(ET_EDGES);
    float* el2 = alloc(ET_EDGES);
    float* fin = alloc((size_t)N_ROOTS * 1128);
    float* fch = alloc((size_t)N_ROOTS * 300);
    float* wallf = alloc(512 * 2048 / 2);
    float* wqkvTf = alloc(768 * 256 / 2);
    float* woTf = alloc(256 * 256 / 2);
    float* bqkv = alloc(768);
    float* wg1Tf = alloc(128 * 128 / 2);
    float* wc1Tf = alloc(128 * 128 / 2);
    float* wg2Tf = alloc(128 * 512 / 2);
    (void)ws_size;
    (void)in_sizes;
    (void)n_in;
    (void)out_size;

    unsigned short* tbuf = (unsigned short*)h1;  // 2048*24*256 bf16 fits in h1+h2
    __hip_bfloat16* wall = (__hip_bfloat16*)wallf;
    short* wqkvT = (short*)wqkvTf;
    short* woT = (short*)woTf;
    short* wg1T = (short*)wg1Tf;
    short* wc1T = (short*)wc1Tf;
    short* wg2T = (short*)wg2Tf;
    float* Cbuf = cat;

    hipMemsetAsync(g2o, 0, zero_floats * sizeof(float), stream);
    init_cat<<<cdiv((long long)N_NODES * 256, 256), 256, 0, stream>>>(cat, gat1_b, gcn1_b);
    fill_i32<<<cdiv(2 * N_NODES, 256), 256, 0, stream>>>(m1, (int)0x80000000, 2 * N_NODES);
    repack_wall<<<cdiv(512 * 2048, 256), 256, 0, stream>>>(cw0, cw1, cw2, cw3, wall);
    repack_xf<<<cdiv(768 * 256, 256), 256, 0, stream>>>(Wq, Wk, Wv, Wo, bq, bk, bv, wqkvT, woT, bqkv);
    repack_wT<<<cdiv(128 * 128, 256), 256, 0, stream>>>(gat1_W, wg1T, 128, 128);
    repack_wT<<<cdiv(128 * 128, 256), 256, 0, stream>>>(gcn1_W, wc1T, 128, 128);
    repack_wT<<<cdiv(512 * 128, 256), 256, 0, stream>>>(gat2_W, wg2T, 512, 128);

    // GAT1 / GCN1 node transforms (MFMA)
    mfma_gemm_n128<<<N_NODES / 128, 256, 0, stream>>>(x2, wg1T, h1, 128);
    mfma_gemm_n128<<<N_NODES / 128, 256, 0, stream>>>(x2, wc1T, h2, 128);
    alpha_kernel<<<cdiv((long long)N_NODES * 64, 256), 256, 0, stream>>>(h1, gat1_as, gat1_ad, als1, ald1);
    edge_p1<<<cdiv(ET_EDGES, 256), 256, 0, stream>>>(ei, als1, ald1, el1, m1, deg);
    edge_p2<<<cdiv(ET_EDGES, 256), 256, 0, stream>>>(ei, el1, m1, den1);
    dinv_kernel<<<cdiv(N_NODES, 256), 256, 0, stream>>>(deg);
    const int sc_blocks4 = cdiv((long long)ET_EDGES * 32, 256);
    // fused GAT1+GCN1 scatter (float4/thread) with inline softmax normalization
    scatter_fused1<<<sc_blocks4, 256, 0, stream>>>(ei, el1, den1, deg, h1, h2, cat);
    // transformer (MFMA): all nodes -> t_avg into cat[:,256:512]
    xformer_kernel<0><<<N_NODES / 2, 256, 0, stream>>>(emb, text2, wqkvT, bqkv, woT, bo, lng, lnb, rooti, rpi, cat,
                                                       nullptr);
    // transformer (MFMA): conv slots -> tbuf (h1/h2 dead after scatters)
    xformer_kernel<1><<<2 * N_ROOTS / 2, 256, 0, stream>>>(emb, text2, wqkvT, bqkv, woT, bo, lng, lnb, rooti, rpi,
                                                           nullptr, tbuf);
    // GAT2 (MFMA, K=512; cat rows are exactly K-contiguous)
    mfma_gemm_n128<<<N_NODES / 128, 256, 0, stream>>>(cat, wg2T, hg2, 512);
    alpha_kernel<<<cdiv((long long)N_NODES * 64, 256), 256, 0, stream>>>(hg2, gat2_as, gat2_ad, als2, ald2);
    edge_p1<<<cdiv(ET_EDGES, 256), 256, 0, stream>>>(ei, als2, ald2, el2, m2, nullptr);
    edge_p2<<<cdiv(ET_EDGES, 256), 256, 0, stream>>>(ei, el2, m2, den2);
    edge_scatter_div<<<sc_blocks4, 256, 0, stream>>>(ei, el2, den2, hg2, g2o);
    // conv branch
    conv_gemm<<<192 * 4, 256, 0, stream>>>((const short*)tbuf, (const short*)wall, Cbuf);
    root_gather<<<cdiv(N_ROOTS * FEAT, 256), 256, 0, stream>>>(g2o, rooti, gat2_b, fin);
    conv_maxpool<<<cdiv(2048 * 500, 256), 256, 0, stream>>>(Cbuf, cb0, cb1, cb2, cb3, fin);
    // head
    gemm64<<<dim3(cdiv(300, 64), cdiv(N_ROOTS, 64)), 256, 0, stream>>>(fin, fc1_W, fc1_b, fch, N_ROOTS, 300, 1128,
                                                                       1128, 300, 1);
    fc2_kernel<<<cdiv(N_ROOTS * 3, 256), 256, 0, stream>>>(fch, fc2_W, fc2_b, (float*)d_out);
}

// Round 11
// 2003.201 us; speedup vs baseline: 1.3177x; 1.3177x over previous
//
#include <hip/hip_runtime.h>
#include <hip/hip_bf16.h>
#include <cstdint>
#include <cstddef>

#define N_NODES 32768
#define N_EDGES 131072
#define ET_EDGES (N_EDGES + N_NODES)
#define N_ROOTS 1024
#define EMB_D 256
#define FEAT 128
#define SEQ 16
#define OUT_CH 125

static inline int cdiv(long long a, long long b) { return (int)((a + b - 1) / b); }

typedef short short8 __attribute__((ext_vector_type(8)));
typedef short short4v __attribute__((ext_vector_type(4)));
typedef float f32x4 __attribute__((ext_vector_type(4)));

// ---------- small utils ----------
__device__ __forceinline__ float warpReduceSum(float v) {
#pragma unroll
    for (int m = 32; m; m >>= 1) v += __shfl_xor(v, m, 64);
    return v;
}
__device__ __forceinline__ int encf(float f) {
    int i = __float_as_int(f);
    return i >= 0 ? i : (i ^ 0x7fffffff);
}
__device__ __forceinline__ float decf(int i) {
    return __int_as_float(i >= 0 ? i : (i ^ 0x7fffffff));
}
// fp32 -> bf16 (RNE) scalar
__device__ __forceinline__ short f2bs(float x) {
    unsigned u = __float_as_uint(x);
    u += 0x7fffu + ((u >> 16) & 1u);
    return (short)(u >> 16);
}
// packed pair (v_cvt_pk_bf16_f32)
__device__ __forceinline__ short2 f2bs2(float a, float b) {
    union {
        __hip_bfloat162 h;
        short2 s;
    } u;
    u.h = __float22bfloat162_rn(make_float2(a, b));
    return u.s;
}
__device__ __forceinline__ float bs2f(short s) {
    return __uint_as_float(((unsigned)(unsigned short)s) << 16);
}

__global__ void fill_i32(int* p, int v, int n) {
    int i = blockIdx.x * 256 + threadIdx.x;
    if (i < n) p[i] = v;
}

// cat cols 0..255 pre-initialized with GAT1/GCN1 biases (scatters accumulate on top)
__global__ void init_cat(float* __restrict__ cat, const float* __restrict__ b1, const float* __restrict__ b2) {
    int i = blockIdx.x * 256 + threadIdx.x;  // over N*256
    int n = i >> 8, c = i & 255;
    float b = (c < 128) ? b1[c] : b2[c - 128];
    cat[(size_t)n * 512 + c] = b;
}

// pack all 4 conv kernels into W_all[512][2048] bf16 (row=(Kidx*125+oc), col=k*256+ic)
__global__ void repack_wall(const float* __restrict__ cw0, const float* __restrict__ cw1,
                            const float* __restrict__ cw2, const float* __restrict__ cw3,
                            __hip_bfloat16* __restrict__ wall) {
    int i = blockIdx.x * 256 + threadIdx.x;
    if (i >= 512 * 2048) return;
    int r = i >> 11, c = i & 2047;
    int k = c >> 8, ic = c & 255;
    float v = 0.f;
    if (r < 500) {
        int Kidx = r / 125, oc = r - Kidx * 125;
        int K = 5 + Kidx;
        if (k < K) {
            const float* cw = Kidx == 0 ? cw0 : Kidx == 1 ? cw1 : Kidx == 2 ? cw2 : cw3;
            v = cw[((size_t)oc * 256 + ic) * K + k];
        }
    }
    wall[i] = __float2bfloat16(v);
}

// transformer weights: wqkvT[768][256] bf16, woT[256][256], bqkv[768]
__global__ void repack_xf(const float* __restrict__ Wq, const float* __restrict__ Wk, const float* __restrict__ Wv,
                          const float* __restrict__ Wo, const float* __restrict__ bq, const float* __restrict__ bk,
                          const float* __restrict__ bv, short* __restrict__ wqkvT, short* __restrict__ woT,
                          float* __restrict__ bqkv) {
    int i = blockIdx.x * 256 + threadIdx.x;
    if (i < 768 * 256) {
        int n = i >> 8, k = i & 255;
        const float* W = n < 256 ? Wq : n < 512 ? Wk : Wv;
        wqkvT[i] = f2bs(W[k * 256 + (n & 255)]);
    }
    if (i < 256 * 256) {
        int n = i >> 8, k = i & 255;
        woT[i] = f2bs(Wo[k * 256 + n]);
    }
    if (i < 768) bqkv[i] = i < 256 ? bq[i] : i < 512 ? bk[i - 256] : bv[i - 512];
}

// generic W[K][N] fp32 -> Wt[N][K] bf16
__global__ void repack_wT(const float* __restrict__ W, short* __restrict__ out, int K, int N) {
    int i = blockIdx.x * 256 + threadIdx.x;
    if (i >= K * N) return;
    int n = i / K, k = i - n * K;
    out[i] = f2bs(W[(size_t)k * N + n]);
}

// ---------- MFMA GEMM: C[M,128] = A[M,K]fp32 @ Wt[128,K]bf16^T ; M mult of 128, K mult of 32 ----------
__global__ __launch_bounds__(256) void mfma_gemm_n128(const float* __restrict__ A, const short* __restrict__ Wt,
                                                      float* __restrict__ C, int K) {
    __shared__ short As[128 * 40];
    __shared__ short Bs[128 * 40];
    const int m0 = blockIdx.x * 128;
    const int tid = threadIdx.x;
    const int lane = tid & 63;
    const int wave = tid >> 6;
    const int wm = (wave >> 1) * 64, wn = (wave & 1) * 64;
    const int quad = lane >> 4, l16 = lane & 15;

    const int r0 = tid >> 2, kc = (tid & 3) * 8;
    const int r1 = r0 + 64;

    f32x4 acc[4][4];
#pragma unroll
    for (int i = 0; i < 4; i++)
#pragma unroll
        for (int j = 0; j < 4; j++) acc[i][j] = (f32x4){0.f, 0.f, 0.f, 0.f};

    for (int k0 = 0; k0 < K; k0 += 32) {
#pragma unroll
        for (int rr = 0; rr < 2; rr++) {
            const int r = rr ? r1 : r0;
            const float* pa = A + (size_t)(m0 + r) * K + k0 + kc;
            float4 a0 = ((const float4*)pa)[0], a1 = ((const float4*)pa)[1];
            short2 c0 = f2bs2(a0.x, a0.y), c1 = f2bs2(a0.z, a0.w), c2 = f2bs2(a1.x, a1.y), c3 = f2bs2(a1.z, a1.w);
            *(short8*)(As + r * 40 + kc) = (short8){c0.x, c0.y, c1.x, c1.y, c2.x, c2.y, c3.x, c3.y};
        }
        *(short8*)(Bs + r0 * 40 + kc) = *(const short8*)(Wt + (size_t)r0 * K + k0 + kc);
        *(short8*)(Bs + r1 * 40 + kc) = *(const short8*)(Wt + (size_t)r1 * K + k0 + kc);
        __syncthreads();
        short8 af[4], bfr[4];
#pragma unroll
        for (int i = 0; i < 4; i++) af[i] = *(const short8*)(As + (wm + i * 16 + l16) * 40 + quad * 8);
#pragma unroll
        for (int j = 0; j < 4; j++) bfr[j] = *(const short8*)(Bs + (wn + j * 16 + l16) * 40 + quad * 8);
#pragma unroll
        for (int i = 0; i < 4; i++)
#pragma unroll
            for (int j = 0; j < 4; j++)
                acc[i][j] = __builtin_amdgcn_mfma_f32_16x16x32_bf16(af[i], bfr[j], acc[i][j], 0, 0, 0);
        __syncthreads();
    }
#pragma unroll
    for (int i = 0; i < 4; i++) {
#pragma unroll
        for (int j = 0; j < 4; j++) {
            const int col = wn + j * 16 + l16;
            const size_t base = (size_t)(m0 + wm + i * 16 + quad * 4) * 128 + col;
#pragma unroll
            for (int r = 0; r < 4; r++) C[base + (size_t)r * 128] = acc[i][j][r];
        }
    }
}

// ---------- generic fp32 GEMM (head fc1 only) ----------
__global__ __launch_bounds__(256) void gemm64(const float* __restrict__ A, const float* __restrict__ B,
                                              const float* __restrict__ bias, float* __restrict__ C,
                                              int M, int N, int K, int lda, int ldc, int doRelu) {
    __shared__ float As[16][65];
    __shared__ float Bs[16][65];
    const int bm = blockIdx.y * 64, bn = blockIdx.x * 64;
    const int tid = threadIdx.x;
    const int tx = tid & 15, ty = tid >> 4;
    float acc[4][4] = {};
    for (int k0 = 0; k0 < K; k0 += 16) {
#pragma unroll
        for (int j = 0; j < 4; j++) {
            int i = tid + j * 256;
            int kk = i & 15, m = i >> 4;
            int gr = bm + m, gc = k0 + kk;
            As[kk][m] = (gr < M && gc < K) ? A[(size_t)gr * lda + gc] : 0.f;
        }
#pragma unroll
        for (int j = 0; j < 4; j++) {
            int i = tid + j * 256;
            int n = i & 63, kk = i >> 6;
            int gr = k0 + kk, gc = bn + n;
            Bs[kk][n] = (gr < K && gc < N) ? B[(size_t)gr * N + gc] : 0.f;
        }
        __syncthreads();
#pragma unroll
        for (int kk = 0; kk < 16; kk++) {
            float a[4], b[4];
#pragma unroll
            for (int i2 = 0; i2 < 4; i2++) a[i2] = As[kk][ty * 4 + i2];
#pragma unroll
            for (int j2 = 0; j2 < 4; j2++) b[j2] = Bs[kk][tx * 4 + j2];
#pragma unroll
            for (int i2 = 0; i2 < 4; i2++)
#pragma unroll
                for (int j2 = 0; j2 < 4; j2++) acc[i2][j2] = fmaf(a[i2], b[j2], acc[i2][j2]);
        }
        __syncthreads();
    }
#pragma unroll
    for (int i2 = 0; i2 < 4; i2++) {
        int r = bm + ty * 4 + i2;
        if (r >= M) continue;
#pragma unroll
        for (int j2 = 0; j2 < 4; j2++) {
            int c = bn + tx * 4 + j2;
            if (c >= N) continue;
            float v = acc[i2][j2];
            if (bias) v += bias[c];
            if (doRelu) v = fmaxf(v, 0.f);
            C[(size_t)r * ldc + c] = v;
        }
    }
}

// ---------- GAT alphas ----------
__global__ __launch_bounds__(256) void alpha_kernel(const float* __restrict__ h, const float* __restrict__ asrc,
                                                    const float* __restrict__ adst, float* __restrict__ als,
                                                    float* __restrict__ ald) {
    int gw = (blockIdx.x * 256 + threadIdx.x) >> 6;
    int lane = threadIdx.x & 63;
    if (gw >= N_NODES) return;
    const float* row = h + (size_t)gw * FEAT;
    float v0 = row[lane], v1 = row[lane + 64];
    float ps = v0 * asrc[lane] + v1 * asrc[lane + 64];
    float pd = v0 * adst[lane] + v1 * adst[lane + 64];
    ps = warpReduceSum(ps);
    pd = warpReduceSum(pd);
    if (lane == 0) {
        als[gw] = ps;
        ald[gw] = pd;
    }
}

// ---------- edge passes ----------
__device__ __forceinline__ void edge_decode(int i, const int* __restrict__ ei, int& s, int& d) {
    if (i < N_EDGES) {
        s = ei[i];
        d = ei[N_EDGES + i];
    } else {
        s = d = i - N_EDGES;
    }
}

__global__ void edge_p1(const int* __restrict__ ei, const float* __restrict__ als, const float* __restrict__ ald,
                        float* __restrict__ elog, int* __restrict__ menc, float* dega) {
    int i = blockIdx.x * 256 + threadIdx.x;
    if (i >= ET_EDGES) return;
    int s, d;
    edge_decode(i, ei, s, d);
    float e = als[s] + ald[d];
    e = (e >= 0.f) ? e : 0.2f * e;
    elog[i] = e;
    atomicMax(&menc[d], encf(e));
    if (dega) unsafeAtomicAdd(&dega[d], 1.f);
}

__global__ void edge_p2(const int* __restrict__ ei, float* __restrict__ elog, const int* __restrict__ menc,
                        float* __restrict__ den) {
    int i = blockIdx.x * 256 + threadIdx.x;
    if (i >= ET_EDGES) return;
    int s, d;
    edge_decode(i, ei, s, d);
    float ex = __expf(elog[i] - decf(menc[d]));
    elog[i] = ex;
    unsafeAtomicAdd(&den[d], ex);
}

__global__ void dinv_kernel(float* deg) {
    int i = blockIdx.x * 256 + threadIdx.x;
    if (i < N_NODES) deg[i] = rsqrtf(fmaxf(deg[i], 1.f));
}

// Fused GAT1+GCN1 scatter, per-element (PROVEN round-9 form): consecutive lanes write consecutive
// addresses for one edge -> coalesced wave-level atomics. float4/thread variant measured -630us (R10).
__global__ void scatter_fused1(const int* __restrict__ ei, const float* __restrict__ elog,
                               const float* __restrict__ den, const float* __restrict__ dinv,
                               const float* __restrict__ h1, const float* __restrict__ h2,
                               float* __restrict__ cat) {
    int i = blockIdx.x * 256 + threadIdx.x;
    if (i >= ET_EDGES * FEAT) return;
    int e = i >> 7, f = i & 127;
    int s, d;
    edge_decode(e, ei, s, d);
    float cA = elog[e] / den[d];
    float cG = dinv[s] * dinv[d];
    unsafeAtomicAdd(&cat[(size_t)d * 512 + f], cA * h1[(size_t)s * FEAT + f]);
    unsafeAtomicAdd(&cat[(size_t)d * 512 + 128 + f], cG * h2[(size_t)s * FEAT + f]);
}

// GAT2 scatter with inline den division, per-element (proven round-9 form)
__global__ void edge_scatter_div(const int* __restrict__ ei, const float* __restrict__ elog,
                                 const float* __restrict__ den, const float* __restrict__ h,
                                 float* __restrict__ out) {
    int i = blockIdx.x * 256 + threadIdx.x;
    if (i >= ET_EDGES * FEAT) return;
    int e = i >> 7, f = i & 127;
    int s, d;
    edge_decode(e, ei, s, d);
    float coef = elog[e] / den[d];
    unsafeAtomicAdd(&out[(size_t)d * FEAT + f], coef * h[(size_t)s * FEAT + f]);
}

__global__ void root_gather(const float* __restrict__ g2, const int* __restrict__ rooti, const float* __restrict__ gb,
                            float* __restrict__ fin) {
    int i = blockIdx.x * 256 + threadIdx.x;
    if (i >= N_ROOTS * FEAT) return;
    int r = i >> 7, c = i & 127;
    fin[(size_t)r * 1128 + c] = g2[(size_t)rooti[r] * FEAT + c] + gb[c];
}

__global__ void fc2_kernel(const float* __restrict__ fch, const float* __restrict__ W, const float* __restrict__ b,
                           float* __restrict__ out) {
    int i = blockIdx.x * 256 + threadIdx.x;
    if (i >= N_ROOTS * 3) return;
    int r = i / 3, c = i - r * 3;
    float acc = b[c];
    for (int k = 0; k < 300; k++) acc = fmaf(fch[(size_t)r * 300 + k], W[k * 3 + c], acc);
    out[i] = acc;
}

// ================= MFMA transformer v9 (PROVEN BEST: 1166-1180us, 84 VGPR, 35% occ) =================
// Occupancy law (10 rounds): waves/SIMD = floor(256 / VGPR) (unified-file scheduling budget
// ~256/SIMD), then LDS caps blocks. v9: 84 regs -> 3 waves/SIMD; 48KB LDS -> 3 blocks; both bind
// at 12 waves/CU (35%). All escapes measured closed: cap<live spills (R0/1/6/7), more ILP spills
// (R5), 512-thr quantizes worse (R8), async B-ring / big-GEMM restructure EV-neutral on paper.
// LDS layout: addr(shorts) = row*256 + (col ^ ((row&7)<<3)). XOR hits byte-bits 4-6 (16-B granule).
__device__ __forceinline__ int lsw(int row, int col) {
    return row * 256 + (col ^ ((row & 7) << 3));
}

// vT layout (wave-private): addr(shorts) = d*32 + swizzled key
__device__ __forceinline__ int vt_addr(int d, int key) {
    return d * 32 + (((key & 24) ^ (((d ^ (d >> 2)) & 3) << 3)) | (key & 7));
}

template <int MODE>
__global__ __launch_bounds__(256, 3) void xformer_kernel(
    const float* __restrict__ emb, const int* __restrict__ text2, const short* __restrict__ wqkvT,
    const float* __restrict__ bqkv, const short* __restrict__ woT, const float* __restrict__ bo,
    const float* __restrict__ lng, const float* __restrict__ lnb, const int* __restrict__ rooti,
    const int* __restrict__ rpi, float* __restrict__ cat, unsigned short* __restrict__ tbuf) {
    __shared__ short qa[32 * 256];    // Q -> P-scratch -> attn-out -> fp32 LN scratch
    __shared__ short kreg[32 * 256];  // A-tile -> y
    __shared__ short vbuf[32 * 256];  // per-wave 2048-short regions: K -> vT
    // total LDS 49152 B -> 3 blocks/CU

    const int tid = threadIdx.x;
    const int wave = tid >> 6, lane = tid & 63;
    const int quad = lane >> 4, l16 = lane & 15;

    int gnode[2];
#pragma unroll
    for (int m = 0; m < 2; m++) {
        int slot = blockIdx.x * 2 + m;
        gnode[m] = (MODE == 0) ? slot : ((slot < N_ROOTS) ? rooti[slot] : rpi[slot - N_ROOTS]);
    }

    // ---- Stage A-tile (2 nodes x 16 rows x 256 cols, bf16) into kreg; one gather pass ----
    {
        const int row = tid >> 3, seg = tid & 7;  // row 0..31, seg 0..7 (32 cols each)
        const int m = row >> 4, r = row & 15;
        const int tok = text2[gnode[m] * SEQ + r];
        const float* ep = emb + (size_t)tok * 256 + seg * 32;
#pragma unroll
        for (int j = 0; j < 4; j++) {
            float4 ea = ((const float4*)(ep + j * 8))[0];
            float4 eb = ((const float4*)(ep + j * 8))[1];
            short2 w0 = f2bs2(ea.x, ea.y), w1 = f2bs2(ea.z, ea.w);
            short2 w2 = f2bs2(eb.x, eb.y), w3 = f2bs2(eb.z, eb.w);
            *(short8*)(kreg + lsw(row, seg * 32 + j * 8)) =
                (short8){w0.x, w0.y, w1.x, w1.y, w2.x, w2.y, w3.x, w3.y};
        }
    }
    __syncthreads();

    // Half-GEMM: 2 output col-tiles (32 cols), acc[2][2], 1-deep B prefetch.
    auto run_gemm_h = [&](const short* __restrict__ W, int wrow0, const short* __restrict__ Albase,
                          f32x4(&acc)[2][2]) {
#pragma unroll
        for (int i = 0; i < 2; i++) {
            acc[i][0] = (f32x4){0.f, 0.f, 0.f, 0.f};
            acc[i][1] = (f32x4){0.f, 0.f, 0.f, 0.f};
        }
        const short* wb = W + (size_t)(wrow0 + l16) * 256 + quad * 8;
        short8 B0 = *(const short8*)(wb);
        short8 B1 = *(const short8*)(wb + 16 * 256);
#pragma unroll
        for (int k0 = 0; k0 < 8; k0++) {
            short8 B0n, B1n;
            if (k0 < 7) {
                B0n = *(const short8*)(wb + (k0 + 1) * 32);
                B1n = *(const short8*)(wb + 16 * 256 + (k0 + 1) * 32);
            }
            short8 A0 = *(const short8*)(Albase + lsw(l16, k0 * 32 + quad * 8));
            short8 A1 = *(const short8*)(Albase + lsw(16 + l16, k0 * 32 + quad * 8));
            acc[0][0] = __builtin_amdgcn_mfma_f32_16x16x32_bf16(A0, B0, acc[0][0], 0, 0, 0);
            acc[0][1] = __builtin_amdgcn_mfma_f32_16x16x32_bf16(A1, B0, acc[0][1], 0, 0, 0);
            acc[1][0] = __builtin_amdgcn_mfma_f32_16x16x32_bf16(A0, B1, acc[1][0], 0, 0, 0);
            acc[1][1] = __builtin_amdgcn_mfma_f32_16x16x32_bf16(A1, B1, acc[1][1], 0, 0, 0);
            B0 = B0n;
            B1 = B1n;
        }
    };

    // K private-layout address inside this wave's vbuf region (row 0..31, c 0..63)
    auto kpriv = [&](int row, int c) { return wave * 2048 + row * 64 + (c ^ ((row & 7) << 3)); };

    f32x4 acc[2][2];

    // ---- Phase 1a: Q halves -> qa (wave-local cols) ----
#pragma unroll 1
    for (int hh = 0; hh < 2; hh++) {
        run_gemm_h(wqkvT, (wave * 4 + hh * 2) * 16, kreg, acc);
#pragma unroll
        for (int ii = 0; ii < 2; ii++) {
            const int col = (wave * 4 + hh * 2 + ii) * 16 + l16;
            const float b = bqkv[col];
#pragma unroll
            for (int m = 0; m < 2; m++) {
                const int rbase = m * 16 + quad * 4;
                short2 p01 = f2bs2((acc[ii][m][0] + b) * 0.25f, (acc[ii][m][1] + b) * 0.25f);
                short2 p23 = f2bs2((acc[ii][m][2] + b) * 0.25f, (acc[ii][m][3] + b) * 0.25f);
                qa[lsw(rbase + 0, col)] = p01.x;
                qa[lsw(rbase + 1, col)] = p01.y;
                qa[lsw(rbase + 2, col)] = p23.x;
                qa[lsw(rbase + 3, col)] = p23.y;
            }
        }
    }
    // ---- Phase 1b: K halves -> vbuf private region (only this wave reads its K cols) ----
#pragma unroll 1
    for (int hh = 0; hh < 2; hh++) {
        run_gemm_h(wqkvT, (16 + wave * 4 + hh * 2) * 16, kreg, acc);
#pragma unroll
        for (int ii = 0; ii < 2; ii++) {
            const int i = hh * 2 + ii;
            const int c = i * 16 + l16;
            const float b = bqkv[(16 + wave * 4 + i) * 16 + l16];
#pragma unroll
            for (int m = 0; m < 2; m++) {
                const int rbase = m * 16 + quad * 4;
                short2 p01 = f2bs2(acc[ii][m][0] + b, acc[ii][m][1] + b);
                short2 p23 = f2bs2(acc[ii][m][2] + b, acc[ii][m][3] + b);
                vbuf[kpriv(rbase + 0, c)] = p01.x;
                vbuf[kpriv(rbase + 1, c)] = p01.y;
                vbuf[kpriv(rbase + 2, c)] = p23.x;
                vbuf[kpriv(rbase + 3, c)] = p23.y;
            }
        }
    }
    // Q/K for heads wave*4..+3 are wave-local: no barrier.

    // ---- Phase 2a: S = K·Q^T per (node, head); softmax per column; P -> qa scratch ----
#pragma unroll
    for (int p = 0; p < 2; p++) {
#pragma unroll
        for (int i = 0; i < 4; i++) {
            const int h = wave * 4 + i;
            const int arow = p * 16 + l16;
            const int q8 = (quad & 1) * 8;
            short8 Af = *(const short8*)(vbuf + kpriv(arow, i * 16 + q8));
            short8 Bf = *(const short8*)(qa + lsw(arow, h * 16 + q8));
            if (quad >= 2) {
                Af = (short8){0, 0, 0, 0, 0, 0, 0, 0};
                Bf = (short8){0, 0, 0, 0, 0, 0, 0, 0};
            }
            f32x4 S = __builtin_amdgcn_mfma_f32_16x16x32_bf16(Af, Bf, (f32x4){0.f, 0.f, 0.f, 0.f}, 0, 0, 0);
            float mx = fmaxf(fmaxf(S[0], S[1]), fmaxf(S[2], S[3]));
            mx = fmaxf(mx, __shfl_xor(mx, 16));
            mx = fmaxf(mx, __shfl_xor(mx, 32));
            float e0 = __expf(S[0] - mx), e1 = __expf(S[1] - mx);
            float e2 = __expf(S[2] - mx), e3 = __expf(S[3] - mx);
            float sm = (e0 + e1) + (e2 + e3);
            sm += __shfl_xor(sm, 16);
            sm += __shfl_xor(sm, 32);
            const float inv = 1.f / sm;
            short2 p01 = f2bs2(e0 * inv, e1 * inv), p23 = f2bs2(e2 * inv, e3 * inv);
            *(short4v*)(qa + lsw(arow, h * 16 + quad * 4)) = (short4v){p01.x, p01.y, p23.x, p23.y};
        }
    }

    // ---- Phase 1c: V halves -> vT straight into vbuf private region (this wave's K is dead) ----
#pragma unroll 1
    for (int hh = 0; hh < 2; hh++) {
        run_gemm_h(wqkvT, (32 + wave * 4 + hh * 2) * 16, kreg, acc);
#pragma unroll
        for (int ii = 0; ii < 2; ii++) {
            const int i = hh * 2 + ii;
            const int d = (wave * 4 + i) * 16 + l16;
            const float b = bqkv[(32 + wave * 4 + i) * 16 + l16];
#pragma unroll
            for (int m = 0; m < 2; m++) {
                const int rbase = m * 16 + quad * 4;
                short2 p01 = f2bs2(acc[ii][m][0] + b, acc[ii][m][1] + b);
                short2 p23 = f2bs2(acc[ii][m][2] + b, acc[ii][m][3] + b);
                *(short4v*)(vbuf + vt_addr(d, rbase)) = (short4v){p01.x, p01.y, p23.x, p23.y};
            }
        }
    }

    // ---- Phase 2c: O^T = V^T · P ; O overwrites P-scratch (all wave-local) ----
#pragma unroll
    for (int p = 0; p < 2; p++) {
#pragma unroll
        for (int i = 0; i < 4; i++) {
            const int h = wave * 4 + i;
            const int arow = p * 16 + l16;
            const int q8 = (quad & 1) * 8;
            short8 BP = *(const short8*)(qa + lsw(arow, h * 16 + q8));
            short8 Av = *(const short8*)(vbuf + vt_addr(h * 16 + l16, p * 16 + q8));
            if (quad >= 2) {
                BP = (short8){0, 0, 0, 0, 0, 0, 0, 0};
                Av = (short8){0, 0, 0, 0, 0, 0, 0, 0};
            }
            f32x4 O = __builtin_amdgcn_mfma_f32_16x16x32_bf16(Av, BP, (f32x4){0.f, 0.f, 0.f, 0.f}, 0, 0, 0);
            short2 o01 = f2bs2(O[0], O[1]), o23 = f2bs2(O[2], O[3]);
            *(short4v*)(qa + lsw(arow, h * 16 + quad * 4)) = (short4v){o01.x, o01.y, o23.x, o23.y};
        }
    }
    __syncthreads();  // attn-out crosses waves for O-proj; all A-tile (kreg) reads done

    // ---- Phase 3: O-proj halves (+bo) -> y into kreg (A-tile dead) ----
#pragma unroll 1
    for (int hh = 0; hh < 2; hh++) {
        run_gemm_h(woT, (wave * 4 + hh * 2) * 16, qa, acc);
#pragma unroll
        for (int ii = 0; ii < 2; ii++) {
            const int col = (wave * 4 + hh * 2 + ii) * 16 + l16;
            const float bocol = bo[col];
#pragma unroll
            for (int m = 0; m < 2; m++) {
                const int rbase = m * 16 + quad * 4;
                short2 a01 = f2bs2(acc[ii][m][0] + bocol, acc[ii][m][1] + bocol);
                short2 a23 = f2bs2(acc[ii][m][2] + bocol, acc[ii][m][3] + bocol);
                kreg[lsw(rbase + 0, col)] = a01.x;
                kreg[lsw(rbase + 1, col)] = a01.y;
                kreg[lsw(rbase + 2, col)] = a23.x;
                kreg[lsw(rbase + 3, col)] = a23.y;
            }
        }
    }
    __syncthreads();

    // ---- Phase 4: residual (emb re-read, L2-hot) + LayerNorm ----
    float* qs = (float*)qa;  // qa dead
    {
        const int row = tid >> 3, seg = tid & 7;
        const int m = row >> 4, r = row & 15;
        const int tokr = text2[gnode[m] * SEQ + r];
        const float* ep = emb + (size_t)tokr * 256 + seg * 32;
        float sum = 0.f, sq = 0.f;
#pragma unroll
        for (int j = 0; j < 4; j++) {
            const int base = lsw(row, seg * 32 + j * 8);
            short8 y8 = *(const short8*)(kreg + base);
            float4 ea = ((const float4*)(ep + j * 8))[0];
            float4 eb = ((const float4*)(ep + j * 8))[1];
            float evv[8] = {ea.x, ea.y, ea.z, ea.w, eb.x, eb.y, eb.z, eb.w};
            float yv[8];
#pragma unroll
            for (int e = 0; e < 8; e++) {
                yv[e] = bs2f(y8[e]) + evv[e];
                sum += yv[e];
                sq = fmaf(yv[e], yv[e], sq);
            }
            short2 w0 = f2bs2(yv[0], yv[1]), w1 = f2bs2(yv[2], yv[3]);
            short2 w2 = f2bs2(yv[4], yv[5]), w3 = f2bs2(yv[6], yv[7]);
            *(short4v*)(kreg + base) = (short4v){w0.x, w0.y, w1.x, w1.y};
            *(short4v*)(kreg + base + 4) = (short4v){w2.x, w2.y, w3.x, w3.y};
        }
        qs[tid] = sum;
        qs[256 + tid] = sq;
    }
    __syncthreads();
    if (tid < 32) {
        float s = 0.f, q2 = 0.f;
#pragma unroll
        for (int j = 0; j < 8; j++) {
            s += qs[tid * 8 + j];
            q2 += qs[256 + tid * 8 + j];
        }
        float mu = s * (1.f / 256.f);
        float var = q2 * (1.f / 256.f) - mu * mu;
        qs[512 + tid * 2] = mu;
        qs[512 + tid * 2 + 1] = rsqrtf(var + 1e-5f);
    }
    __syncthreads();
    {
        const int c = tid;
        const float g = lng[c], bb = lnb[c];
        float csum[2] = {0.f, 0.f};
#pragma unroll
        for (int m = 0; m < 2; m++) {
#pragma unroll
            for (int r = 0; r < 16; r++) {
                const int row = m * 16 + r;
                const float yv = bs2f(kreg[lsw(row, c)]);
                const float mu = qs[512 + row * 2], rstd = qs[512 + row * 2 + 1];
                const float o = (yv - mu) * rstd * g + bb;
                if (MODE == 0) {
                    csum[m] += o;
                } else {
                    tbuf[((size_t)(blockIdx.x * 2 + m) * 24 + r) * 256 + c] = (unsigned short)f2bs(o);
                }
            }
        }
        if (MODE == 0) {
            cat[(size_t)gnode[0] * 512 + 256 + c] = csum[0] * (1.f / 16.f);
            cat[(size_t)gnode[1] * 512 + 256 + c] = csum[1] * (1.f / 16.f);
        } else {
            for (int z = tid; z < 2 * 8 * 256; z += 256) {
                const int m = z >> 11, rem = z & 2047;
                tbuf[((size_t)(blockIdx.x * 2 + m) * 24 + 16 + (rem >> 8)) * 256 + (rem & 255)] = 0;
            }
        }
    }
}

// conv GEMM: C[24576,512] = im2col(tbuf) @ W_all^T. Per-n-tile K cap: tiles 0/1 hold kernel sizes
// 5-6/6-7 only, so wall rows are zero beyond K=1536/1792 -> skip guaranteed-zero MFMA (exact).
__global__ __launch_bounds__(256) void conv_gemm(const short* __restrict__ tb, const short* __restrict__ wall,
                                                 float* __restrict__ C) {
    __shared__ short As[128 * 40];
    __shared__ short Bs[128 * 40];
    const int bid = blockIdx.x;
    const int m0 = (bid >> 2) * 128;
    const int n0 = (bid & 3) * 128;
    const int tid = threadIdx.x;
    const int lane = tid & 63;
    const int wave = tid >> 6;
    const int wm = (wave >> 1) * 64, wn = (wave & 1) * 64;
    const int quad = lane >> 4, l16 = lane & 15;

    const int r0 = tid >> 2, kc = (tid & 3) * 8;
    const int r1 = r0 + 64;
    const int am0 = m0 + r0, am1 = m0 + r1;
    const int s0 = am0 / 12, p0_ = am0 - s0 * 12;
    const int s1 = am1 / 12, p1_ = am1 - s1 * 12;
    const size_t ga0 = (size_t)(s0 * 24 + p0_) * 256 + kc;
    const size_t ga1 = (size_t)(s1 * 24 + p1_) * 256 + kc;
    const size_t gb0 = (size_t)(n0 + r0) * 2048 + kc;
    const size_t gb1 = (size_t)(n0 + r1) * 2048 + kc;
    short* sa0 = As + r0 * 40 + kc;
    short* sa1 = As + r1 * 40 + kc;
    short* sb0 = Bs + r0 * 40 + kc;
    short* sb1 = Bs + r1 * 40 + kc;

    const int kmax = (n0 == 0) ? 1536 : (n0 == 128) ? 1792 : 2048;

    f32x4 acc[4][4];
#pragma unroll
    for (int i = 0; i < 4; i++)
#pragma unroll
        for (int j = 0; j < 4; j++) acc[i][j] = (f32x4){0.f, 0.f, 0.f, 0.f};

    for (int k0 = 0; k0 < kmax; k0 += 32) {
        short8 a0 = *(const short8*)(tb + ga0 + k0);
        short8 a1 = *(const short8*)(tb + ga1 + k0);
        short8 b0 = *(const short8*)(wall + gb0 + k0);
        short8 b1 = *(const short8*)(wall + gb1 + k0);
        *(short8*)sa0 = a0;
        *(short8*)sa1 = a1;
        *(short8*)sb0 = b0;
        *(short8*)sb1 = b1;
        __syncthreads();
        short8 af[4], bfr[4];
#pragma unroll
        for (int i = 0; i < 4; i++) af[i] = *(const short8*)(As + (wm + i * 16 + l16) * 40 + quad * 8);
#pragma unroll
        for (int j = 0; j < 4; j++) bfr[j] = *(const short8*)(Bs + (wn + j * 16 + l16) * 40 + quad * 8);
#pragma unroll
        for (int i = 0; i < 4; i++)
#pragma unroll
            for (int j = 0; j < 4; j++)
                acc[i][j] = __builtin_amdgcn_mfma_f32_16x16x32_bf16(af[i], bfr[j], acc[i][j], 0, 0, 0);
        __syncthreads();
    }
#pragma unroll
    for (int i = 0; i < 4; i++) {
#pragma unroll
        for (int j = 0; j < 4; j++) {
            const int col = n0 + wn + j * 16 + l16;
            const size_t base = (size_t)(m0 + wm + i * 16 + quad * 4) * 512 + col;
#pragma unroll
            for (int r = 0; r < 4; r++) C[base + (size_t)r * 512] = acc[i][j][r];
        }
    }
}

__global__ void conv_maxpool(const float* __restrict__ C, const float* __restrict__ cb0, const float* __restrict__ cb1,
                             const float* __restrict__ cb2, const float* __restrict__ cb3, float* __restrict__ fin) {
    int i = blockIdx.x * 256 + threadIdx.x;
    if (i >= 2048 * 500) return;
    int slot = i / 500, q = i - slot * 500;
    int Kidx = q / 125, oc = q - Kidx * 125;
    int L = 12 - Kidx;
    const float* base = C + (size_t)(slot * 12) * 512 + q;
    float m = base[0];
    for (int p = 1; p < L; p++) m = fmaxf(m, base[(size_t)p * 512]);
    float b = (Kidx == 0 ? cb0 : Kidx == 1 ? cb1 : Kidx == 2 ? cb2 : cb3)[oc];
    float v = fmaxf(m + b, 0.f);
    int idx = slot < N_ROOTS ? slot : slot - N_ROOTS;
    int colbase = slot < N_ROOTS ? 128 : 628;
    fin[(size_t)idx * 1128 + colbase + q] = v;
}

// ---------- host launch ----------
extern "C" void kernel_launch(void* const* d_in, const int* in_sizes, int n_in, void* d_out, int out_size, void* d_ws,
                              size_t ws_size, hipStream_t stream) {
    const float* x2 = (const float*)d_in[0];
    const float* emb = (const float*)d_in[1];
    const float* Wq = (const float*)d_in[2];
    const float* Wk = (const float*)d_in[3];
    const float* Wv = (const float*)d_in[4];
    const float* Wo = (const float*)d_in[5];
    const float* bq = (const float*)d_in[6];
    const float* bk = (const float*)d_in[7];
    const float* bv = (const float*)d_in[8];
    const float* bo = (const float*)d_in[9];
    const float* lng = (const float*)d_in[10];
    const float* lnb = (const float*)d_in[11];
    const float* gat1_W = (const float*)d_in[12];
    const float* gat1_as = (const float*)d_in[13];
    const float* gat1_ad = (const float*)d_in[14];
    const float* gat1_b = (const float*)d_in[15];
    const float* gcn1_W = (const float*)d_in[16];
    const float* gcn1_b = (const float*)d_in[17];
    const float* gat2_W = (const float*)d_in[18];
    const float* gat2_as = (const float*)d_in[19];
    const float* gat2_ad = (const float*)d_in[20];
    const float* gat2_b = (const float*)d_in[21];
    // d_in[22]/[23] gcn2: dead code in reference forward
    const float* cw0 = (const float*)d_in[24];
    const float* cb0 = (const float*)d_in[25];
    const float* cw1 = (const float*)d_in[26];
    const float* cb1 = (const float*)d_in[27];
    const float* cw2 = (const float*)d_in[28];
    const float* cb2 = (const float*)d_in[29];
    const float* cw3 = (const float*)d_in[30];
    const float* cb3 = (const float*)d_in[31];
    const float* fc1_W = (const float*)d_in[32];
    const float* fc1_b = (const float*)d_in[33];
    const float* fc2_W = (const float*)d_in[34];
    const float* fc2_b = (const float*)d_in[35];
    const int* text2 = (const int*)d_in[36];
    const int* ei = (const int*)d_in[37];
    const int* rooti = (const int*)d_in[38];
    const int* rpi = (const int*)d_in[39];

    float* ws = (float*)d_ws;
    size_t off = 0;
    auto alloc = [&](size_t n) {
        float* p = ws + off;
        off += n;
        return p;
    };
    // zero block first (one small memset): g2o | den1 | den2 | deg
    float* g2o = alloc((size_t)N_NODES * FEAT);
    float* den1 = alloc(N_NODES);
    float* den2 = alloc(N_NODES);
    float* deg = alloc(N_NODES);
    size_t zero_floats = off;
    float* cat = alloc((size_t)N_NODES * 512);  // init_cat covers cols 0..255; xformer fills 256..511
    float* h1 = alloc((size_t)N_NODES * FEAT);  // h1+h2 reused as tbuf after scatters
    float* h2 = alloc((size_t)N_NODES * FEAT);
    float* hg2 = alloc((size_t)N_NODES * FEAT);
    float* als1 = alloc(N_NODES);
    float* ald1 = alloc(N_NODES);
    float* als2 = alloc(N_NODES);
    float* ald2 = alloc(N_NODES);
    int* m1 = (int*)alloc(N_NODES);
    int* m2 = (int*)alloc(N_NODES);
    float* el1 = alloc(ET_EDGES);
    float* el2 = alloc(ET_EDGES);
    float* fin = alloc((size_t)N_ROOTS * 1128);
    float* fch = alloc((size_t)N_ROOTS * 300);
    float* wallf = alloc(512 * 2048 / 2);
    float* wqkvTf = alloc(768 * 256 / 2);
    float* woTf = alloc(256 * 256 / 2);
    float* bqkv = alloc(768);
    float* wg1Tf = alloc(128 * 128 / 2);
    float* wc1Tf = alloc(128 * 128 / 2);
    float* wg2Tf = alloc(128 * 512 / 2);
    (void)ws_size;
    (void)in_sizes;
    (void)n_in;
    (void)out_size;

    unsigned short* tbuf = (unsigned short*)h1;  // 2048*24*256 bf16 fits in h1+h2
    __hip_bfloat16* wall = (__hip_bfloat16*)wallf;
    short* wqkvT = (short*)wqkvTf;
    short* woT = (short*)woTf;
    short* wg1T = (short*)wg1Tf;
    short* wc1T = (short*)wc1Tf;
    short* wg2T = (short*)wg2Tf;
    float* Cbuf = cat;

    hipMemsetAsync(g2o, 0, zero_floats * sizeof(float), stream);
    init_cat<<<cdiv((long long)N_NODES * 256, 256), 256, 0, stream>>>(cat, gat1_b, gcn1_b);
    fill_i32<<<cdiv(2 * N_NODES, 256), 256, 0, stream>>>(m1, (int)0x80000000, 2 * N_NODES);
    repack_wall<<<cdiv(512 * 2048, 256), 256, 0, stream>>>(cw0, cw1, cw2, cw3, wall);
    repack_xf<<<cdiv(768 * 256, 256), 256, 0, stream>>>(Wq, Wk, Wv, Wo, bq, bk, bv, wqkvT, woT, bqkv);
    repack_wT<<<cdiv(128 * 128, 256), 256, 0, stream>>>(gat1_W, wg1T, 128, 128);
    repack_wT<<<cdiv(128 * 128, 256), 256, 0, stream>>>(gcn1_W, wc1T, 128, 128);
    repack_wT<<<cdiv(512 * 128, 256), 256, 0, stream>>>(gat2_W, wg2T, 512, 128);

    // GAT1 / GCN1 node transforms (MFMA)
    mfma_gemm_n128<<<N_NODES / 128, 256, 0, stream>>>(x2, wg1T, h1, 128);
    mfma_gemm_n128<<<N_NODES / 128, 256, 0, stream>>>(x2, wc1T, h2, 128);
    alpha_kernel<<<cdiv((long long)N_NODES * 64, 256), 256, 0, stream>>>(h1, gat1_as, gat1_ad, als1, ald1);
    edge_p1<<<cdiv(ET_EDGES, 256), 256, 0, stream>>>(ei, als1, ald1, el1, m1, deg);
    edge_p2<<<cdiv(ET_EDGES, 256), 256, 0, stream>>>(ei, el1, m1, den1);
    dinv_kernel<<<cdiv(N_NODES, 256), 256, 0, stream>>>(deg);
    const int sc_blocks = cdiv((long long)ET_EDGES * FEAT, 256);
    // fused GAT1+GCN1 scatter (per-element, coalesced atomics) with inline softmax normalization
    scatter_fused1<<<sc_blocks, 256, 0, stream>>>(ei, el1, den1, deg, h1, h2, cat);
    // transformer (MFMA): all nodes -> t_avg into cat[:,256:512]
    xformer_kernel<0><<<N_NODES / 2, 256, 0, stream>>>(emb, text2, wqkvT, bqkv, woT, bo, lng, lnb, rooti, rpi, cat,
                                                       nullptr);
    // transformer (MFMA): conv slots -> tbuf (h1/h2 dead after scatters)
    xformer_kernel<1><<<2 * N_ROOTS / 2, 256, 0, stream>>>(emb, text2, wqkvT, bqkv, woT, bo, lng, lnb, rooti, rpi,
                                                           nullptr, tbuf);
    // GAT2 (MFMA, K=512; cat rows are exactly K-contiguous)
    mfma_gemm_n128<<<N_NODES / 128, 256, 0, stream>>>(cat, wg2T, hg2, 512);
    alpha_kernel<<<cdiv((long long)N_NODES * 64, 256), 256, 0, stream>>>(hg2, gat2_as, gat2_ad, als2, ald2);
    edge_p1<<<cdiv(ET_EDGES, 256), 256, 0, stream>>>(ei, als2, ald2, el2, m2, nullptr);
    edge_p2<<<cdiv(ET_EDGES, 256), 256, 0, stream>>>(ei, el2, m2, den2);
    edge_scatter_div<<<sc_blocks, 256, 0, stream>>>(ei, el2, den2, hg2, g2o);
    // conv branch
    conv_gemm<<<192 * 4, 256, 0, stream>>>((const short*)tbuf, (const short*)wall, Cbuf);
    root_gather<<<cdiv(N_ROOTS * FEAT, 256), 256, 0, stream>>>(g2o, rooti, gat2_b, fin);
    conv_maxpool<<<cdiv(2048 * 500, 256), 256, 0, stream>>>(Cbuf, cb0, cb1, cb2, cb3, fin);
    // head
    gemm64<<<dim3(cdiv(300, 64), cdiv(N_ROOTS, 64)), 256, 0, stream>>>(fin, fc1_W, fc1_b, fch, N_ROOTS, 300, 1128,
                                                                       1128, 300, 1);
    fc2_kernel<<<cdiv(N_ROOTS * 3, 256), 256, 0, stream>>>(fch, fc2_W, fc2_b, (float*)d_out);
}